// Round 19
// baseline (363.284 us; speedup 1.0000x reference)
//
#include <hip/hip_runtime.h>
#include <hip/hip_bf16.h>
#include <stdint.h>

#define NN 40000
#define EE 640000
#define HD 128
#define TDIM 128
#define TB 128
#define NTILES (EE / TB)   // 5000
#define GRID 768           // persistent: 3 blocks/CU (25.6 KB LDS, ~80 regs)

typedef short  s16x8 __attribute__((ext_vector_type(8)));
typedef float  f32x2 __attribute__((ext_vector_type(2)));
typedef float  f32x4 __attribute__((ext_vector_type(4)));
typedef unsigned short u16;
typedef unsigned int   u32;

#define PSCL 8.0f        // P stored x8 in fp8 e4m3
#define PDSC 0.125f
#define WSCALE 16.0f     // weights stored x16 in fp8; descale 1/16 after MFMA
#define WDSC 0.0625f

__device__ __forceinline__ u32 cvtpk(float lo, float hi) {
  u32 r; asm("v_cvt_pk_bf16_f32 %0, %1, %2" : "=v"(r) : "v"(lo), "v"(hi)); return r;
}
__device__ __forceinline__ u16 f2b(float f) {
  union { float f; u32 u; } x; x.f = f;
  u32 r = x.u + 0x7fffu + ((x.u >> 16) & 1u);
  return (u16)(r >> 16);
}

// ---- launch 1: FiLM params: film[0:128]=shift, film[128:256]=1+scale ----
__global__ void prep_film_kernel(const float* __restrict__ te, const float* __restrict__ tW,
                                 const float* __restrict__ tb, float* __restrict__ film) {
  __shared__ float s[TDIM];
  int t = threadIdx.x;
  if (t < TDIM) { float v = te[t]; s[t] = v * __builtin_amdgcn_rcpf(1.f + __expf(-v)); }
  __syncthreads();
  float acc = tb[t];
  #pragma unroll 8
  for (int k = 0; k < TDIM; ++k) acc = fmaf(s[k], tW[k * 256 + t], acc);
  film[t] = (t >= 128) ? (1.f + acc) : acc;
}

// ---- launch 2 (fused): wPt | wadWt(fp8) | c1Wt(fp8) | biasp ----
//  blocks [0,128):   wPt[256][128] bf16 (prep_P weights)
//  blocks [128,144): GEMM1 fp8 pairs: byte idx = ks*4096+lg*1024+n*128+l15*8+j,
//                    k = ks*32+lg*8+j, row = n*16+l15, val = 16*iW[256+k][row]
//  blocks [144,176): GEMM2 fp8 pairs, k-permuted: ch = (2*kq+(j>>2))*16+lg*4+(j&3),
//                    val = 16*(1+scale[ch])*c1W[ch][n*16+l15]
//  block 176:        biasp[c] = c1b[c] + sum_k shift[k]*c1W[k][c]
__global__ void prep_weights_kernel(const float* __restrict__ iW,
                                    const float* __restrict__ c1W,
                                    const float* __restrict__ film,
                                    const float* __restrict__ c1b,
                                    u16* __restrict__ wPt,
                                    u16* __restrict__ wadWt,
                                    u16* __restrict__ c1Wt,
                                    float* __restrict__ biasp) {
  int b = blockIdx.x, t = threadIdx.x;
  if (b < 128) {
    int idx = b * 256 + t;                 // < 32768
    int c = idx >> 7, k = idx & 127;
    wPt[idx] = f2b(iW[((c >> 7) * 128 + k) * HD + (c & 127)]);
  } else if (b < 144) {
    int pidx = (b - 128) * 256 + t;        // < 4096 fp8 pairs
    int idx = pidx * 2;
    int j0 = idx & 7, l15 = (idx >> 3) & 15, n = (idx >> 7) & 7, lg = (idx >> 10) & 3, ks = idx >> 12;
    int row = n * 16 + l15;
    int k0 = ks * 32 + lg * 8 + j0;
    float v0 = WSCALE * iW[(256 + k0) * HD + row];
    float v1 = WSCALE * iW[(256 + k0 + 1) * HD + row];
    u32 p = __builtin_amdgcn_cvt_pk_fp8_f32(v0, v1, 0, false);
    wadWt[pidx] = (u16)p;
  } else if (b < 176) {
    int pidx = (b - 144) * 256 + t;        // < 8192 fp8 pairs
    int idx = pidx * 2;
    int j0 = idx & 7, l15 = (idx >> 3) & 15, n = (idx >> 7) & 7, lg = (idx >> 10) & 3, kq = idx >> 12;
    int row = n * 16 + l15;
    int ch0 = (kq * 2 + (j0 >> 2)) * 16 + lg * 4 + (j0 & 3);
    int ch1 = (kq * 2 + ((j0 + 1) >> 2)) * 16 + lg * 4 + ((j0 + 1) & 3);
    float v0 = WSCALE * film[128 + ch0] * c1W[ch0 * HD + row];
    float v1 = WSCALE * film[128 + ch1] * c1W[ch1 * HD + row];
    u32 p = __builtin_amdgcn_cvt_pk_fp8_f32(v0, v1, 0, false);
    c1Wt[pidx] = (u16)p;
  } else if (t < 128) {
    float acc = c1b[t];
    #pragma unroll 8
    for (int k = 0; k < 128; ++k) acc = fmaf(film[k], c1W[k * HD + t], acc);
    biasp[t] = acc;
  }
}

// ---- launch 3: P[node] = 64 u32 words of fp8 (x8), fragment-permuted; + pos copy ----
__global__ __launch_bounds__(256) void prep_P_kernel(const float* __restrict__ h,
                                                     const u16* __restrict__ wPt,
                                                     const float* __restrict__ ib,
                                                     const float* __restrict__ pos,
                                                     u32* __restrict__ P,
                                                     float* __restrict__ out) {
  __shared__ u16 sWp[256][136];
  __shared__ float sib[HD];
  int t = threadIdx.x;
  {
    int ci = blockIdx.x * 192 + t;
    if (t < 192) out[ci] = pos[ci];
  }
  if (t < 128) sib[t] = ib[t];
  {
    const u16* src = wPt + t * 128;
    #pragma unroll
    for (int i = 0; i < 16; ++i)
      *(uint4*)&sWp[t][i * 8] = *(const uint4*)(src + i * 8);
  }
  int wave = t >> 6, lane = t & 63, l15 = lane & 15, lg = lane >> 4;
  int node = blockIdx.x * 64 + wave * 16 + l15;
  uint4 hb[4];
  const float* hr = h + (size_t)node * HD + lg * 8;
  #pragma unroll
  for (int c = 0; c < 4; ++c) {
    float4 a = *(const float4*)(hr + c * 32);
    float4 b = *(const float4*)(hr + c * 32 + 4);
    hb[c].x = cvtpk(a.x, a.y); hb[c].y = cvtpk(a.z, a.w);
    hb[c].z = cvtpk(b.x, b.y); hb[c].w = cvtpk(b.z, b.w);
  }
  __syncthreads();
  f32x4 acc[16];
  #pragma unroll
  for (int n = 0; n < 16; ++n) acc[n] = (f32x4){0.f, 0.f, 0.f, 0.f};
  #pragma unroll
  for (int c = 0; c < 4; ++c) {
    s16x8 bF = *(const s16x8*)&hb[c];
    #pragma unroll
    for (int n = 0; n < 16; ++n) {
      s16x8 aF = *(const s16x8*)&sWp[n * 16 + l15][c * 32 + lg * 8];
      acc[n] = __builtin_amdgcn_mfma_f32_16x16x32_bf16(aF, bF, acc[n], 0, 0, 0);
    }
  }
  u32* dst = P + (size_t)node * 64;
  #pragma unroll
  for (int n = 0; n < 16; ++n) {
    int side = n >> 3;
    int cb = (n & 7) * 16 + lg * 4;
    float a0 = acc[n][0], a1 = acc[n][1], a2 = acc[n][2], a3 = acc[n][3];
    if (side == 0) { a0 += sib[cb]; a1 += sib[cb + 1]; a2 += sib[cb + 2]; a3 += sib[cb + 3]; }
    u32 w = __builtin_amdgcn_cvt_pk_fp8_f32(PSCL * a0, PSCL * a1, 0, false);
    w = __builtin_amdgcn_cvt_pk_fp8_f32(PSCL * a2, PSCL * a3, w, true);
    dst[side * 32 + lg * 8 + (n & 7)] = w;
  }
}

// ---- small prefetch state ----
struct PfS {
  int ri, ci;
  float4 a0, a1, d0, d1;
  float p0x, p0y, p0z, p1x, p1y, p1z;
};

// ---- launch 4: persistent fused edge kernel (fp8 weights + fp8 P) ----
__global__ __launch_bounds__(512, 4) void edge_kernel(
    const float* __restrict__ pos,
    const float* __restrict__ edge_attr,
    const float* __restrict__ dist,
    const float* __restrict__ c2w,
    const float* __restrict__ cn_scale,
    const int*   __restrict__ eidx,
    const u32*   __restrict__ P,       // [N][64] u32 of fp8(x8), fragment-permuted
    const u16*   __restrict__ wadWt,   // 8 KB fp8 GEMM1 weights (x16)
    const u16*   __restrict__ c1Wt,    // 16 KB fp8 GEMM2 weights (x16, k-permuted)
    const float* __restrict__ biasp,   // [128]
    float*       __restrict__ out)
{
  __shared__ u16   sW1[4096];    // 8 KB fp8
  __shared__ u16   sW2[8192];    // 16 KB fp8
  __shared__ float sC1b[HD];
  __shared__ float sC2w[HD];

  const int t    = threadIdx.x;
  const int lane = t & 63;
  const int wave = t >> 6;        // 0..7
  const int l15  = lane & 15;
  const int lg   = lane >> 4;
  const int wv   = wave * 16 + l15;   // edge offset in tile, 0..127

  if (t < HD) { sC1b[t] = biasp[t]; sC2w[t] = c2w[t]; }
  {
    const uint4* s1 = (const uint4*)wadWt;   // 512 uint4
    uint4* d1 = (uint4*)sW1;
    if (t < 512) d1[t] = s1[t];
    const uint4* s2 = (const uint4*)c1Wt;    // 1024 uint4
    uint4* d2 = (uint4*)sW2;
    #pragma unroll
    for (int i = 0; i < 2; ++i) d2[t + i * 512] = s2[t + i * 512];
  }

  const float cns = cn_scale[0];
  const int bb8 = lg * 1024 + l15 * 8;   // byte base within each 4KB fp8 k-panel

  auto pf_idx_ad = [&](PfS& p, int tile) {
    int e = tile * TB + wv;
    p.ri = eidx[e];
    p.ci = eidx[EE + e];
    const float* pa = edge_attr + (size_t)e * 32 + lg * 8;
    const float* pd = dist      + (size_t)e * 32 + lg * 8;
    p.a0 = *(const float4*)(pa); p.a1 = *(const float4*)(pa + 4);
    p.d0 = *(const float4*)(pd); p.d1 = *(const float4*)(pd + 4);
  };
  auto pf_pos = [&](PfS& p) {
    p.p0x = pos[p.ri * 3 + 0]; p.p0y = pos[p.ri * 3 + 1]; p.p0z = pos[p.ri * 3 + 2];
    p.p1x = pos[p.ci * 3 + 0]; p.p1y = pos[p.ci * 3 + 1]; p.p1z = pos[p.ci * 3 + 2];
  };

  PfS A, B;
  pf_idx_ad(A, blockIdx.x);
  pf_pos(A);

  // prologue: P gathers (fp8: 2 uint4 per side)
  uint4 pra0, pra1, pca0, pca1;
  {
    const u32* pr = P + (size_t)A.ri * 64 + lg * 8;
    const u32* pc = P + (size_t)A.ci * 64 + 32 + lg * 8;
    pra0 = *(const uint4*)(pr); pra1 = *(const uint4*)(pr + 4);
    pca0 = *(const uint4*)(pc); pca1 = *(const uint4*)(pc + 4);
  }

  __syncthreads();   // only barrier: weights + consts visible

  for (int tile = blockIdx.x; tile < NTILES; tile += GRID) {
    int tn = tile + GRID; if (tn >= NTILES) tn = tile;

    // (1) next tile's independent loads — in flight across this tile
    pf_idx_ad(B, tn);

    // (2) pack features to fp8 (x1; weights carry x16)
    long ef0, ef1;
    {
      u32 a0 = __builtin_amdgcn_cvt_pk_fp8_f32(A.a0.x, A.a0.y, 0, false);
      a0 = __builtin_amdgcn_cvt_pk_fp8_f32(A.a0.z, A.a0.w, a0, true);
      u32 a1 = __builtin_amdgcn_cvt_pk_fp8_f32(A.a1.x, A.a1.y, 0, false);
      a1 = __builtin_amdgcn_cvt_pk_fp8_f32(A.a1.z, A.a1.w, a1, true);
      u32 d0 = __builtin_amdgcn_cvt_pk_fp8_f32(A.d0.x, A.d0.y, 0, false);
      d0 = __builtin_amdgcn_cvt_pk_fp8_f32(A.d0.z, A.d0.w, d0, true);
      u32 d1 = __builtin_amdgcn_cvt_pk_fp8_f32(A.d1.x, A.d1.y, 0, false);
      d1 = __builtin_amdgcn_cvt_pk_fp8_f32(A.d1.z, A.d1.w, d1, true);
      ef0 = (long)(((unsigned long long)a1 << 32) | a0);
      ef1 = (long)(((unsigned long long)d1 << 32) | d0);
    }

    // (3) GEMM1 (fp8): Q = [attr|dist] @ iW_ad, immediate-offset ds_read_b64
    f32x4 acc[8];
    #pragma unroll
    for (int n = 0; n < 8; ++n) acc[n] = (f32x4){0.f, 0.f, 0.f, 0.f};
    #pragma unroll
    for (int ks = 0; ks < 2; ++ks) {
      long bF = (ks == 0) ? ef0 : ef1;
      #pragma unroll
      for (int n = 0; n < 8; ++n) {
        long aF = *(const long*)((const char*)sW1 + ks * 4096 + bb8 + n * 128);
        acc[n] = __builtin_amdgcn_mfma_f32_16x16x32_fp8_fp8(aF, bF, acc[n], 0, 0, 0);
      }
    }

    // (4) x = Q/16 + (P_r + P_c)/8; LN stats with 4-way partial accumulators
    float x[8][4];
    float s0=0.f,s1=0.f,s2=0.f,s3=0.f, q0=0.f,q1=0.f,q2=0.f,q3=0.f;
    #pragma unroll
    for (int i = 0; i < 2; ++i) {
      uint4 wa = (i == 0) ? pra0 : pra1;
      uint4 wc = (i == 0) ? pca0 : pca1;
      #pragma unroll
      for (int k = 0; k < 4; ++k) {
        int n = i * 4 + k;
        u32 aw = (k == 0) ? wa.x : (k == 1) ? wa.y : (k == 2) ? wa.z : wa.w;
        u32 cw = (k == 0) ? wc.x : (k == 1) ? wc.y : (k == 2) ? wc.z : wc.w;
        f32x2 a01 = __builtin_amdgcn_cvt_pk_f32_fp8(aw, false);
        f32x2 a23 = __builtin_amdgcn_cvt_pk_f32_fp8(aw, true);
        f32x2 c01 = __builtin_amdgcn_cvt_pk_f32_fp8(cw, false);
        f32x2 c23 = __builtin_amdgcn_cvt_pk_f32_fp8(cw, true);
        float v0 = fmaf(acc[n][0], WDSC, (a01[0] + c01[0]) * PDSC);
        float v1 = fmaf(acc[n][1], WDSC, (a01[1] + c01[1]) * PDSC);
        float v2 = fmaf(acc[n][2], WDSC, (a23[0] + c23[0]) * PDSC);
        float v3 = fmaf(acc[n][3], WDSC, (a23[1] + c23[1]) * PDSC);
        x[n][0] = v0; x[n][1] = v1; x[n][2] = v2; x[n][3] = v3;
        s0 += v0; s1 += v1; s2 += v2; s3 += v3;
        q0 = fmaf(v0,v0,q0); q1 = fmaf(v1,v1,q1);
        q2 = fmaf(v2,v2,q2); q3 = fmaf(v3,v3,q3);
      }
    }
    float sum = (s0 + s1) + (s2 + s3);
    float sq  = (q0 + q1) + (q2 + q3);
    sum += __shfl_xor(sum, 16); sum += __shfl_xor(sum, 32);
    sq  += __shfl_xor(sq,  16); sq  += __shfl_xor(sq,  32);
    float mean = sum * (1.f / 128.f);
    float var  = sq  * (1.f / 128.f) - mean * mean;
    float LA = rsqrtf(var + 1e-6f);
    float LB = -mean * LA;

    // (5) x-hat -> fp8 words (GEMM2 B-operand, k-permuted)
    u32 xp[8];
    #pragma unroll
    for (int n = 0; n < 8; ++n) {
      float y0 = fmaf(x[n][0], LA, LB);
      float y1 = fmaf(x[n][1], LA, LB);
      float y2 = fmaf(x[n][2], LA, LB);
      float y3 = fmaf(x[n][3], LA, LB);
      u32 w = __builtin_amdgcn_cvt_pk_fp8_f32(y0, y1, 0, false);
      w = __builtin_amdgcn_cvt_pk_fp8_f32(y2, y3, w, true);
      xp[n] = w;
    }

    // (6) GEMM2 (fp8): reuse acc; B from registers, A via immediate-offset ds_read_b64
    #pragma unroll
    for (int n = 0; n < 8; ++n) acc[n] = (f32x4){0.f, 0.f, 0.f, 0.f};
    #pragma unroll
    for (int kq = 0; kq < 4; ++kq) {
      long xF = (long)(((unsigned long long)xp[2*kq+1] << 32) | xp[2*kq]);
      #pragma unroll
      for (int n = 0; n < 8; ++n) {
        long aF = *(const long*)((const char*)sW2 + kq * 4096 + bb8 + n * 128);
        acc[n] = __builtin_amdgcn_mfma_f32_16x16x32_fp8_fp8(aF, xF, acc[n], 0, 0, 0);
      }
    }

    // (7) silu -> dot(c2W) with 4-way partial chains (descale 1/16)
    float z0=0.f, z1=0.f, z2=0.f, z3=0.f;
    #pragma unroll
    for (int n = 0; n < 8; ++n) {
      int cb = n * 16 + lg * 4;
      f32x4 cb4 = *(const f32x4*)&sC1b[cb];
      f32x4 cw4 = *(const f32x4*)&sC2w[cb];
      float y0 = fmaf(acc[n][0], WDSC, cb4[0]);
      float y1 = fmaf(acc[n][1], WDSC, cb4[1]);
      float y2 = fmaf(acc[n][2], WDSC, cb4[2]);
      float y3 = fmaf(acc[n][3], WDSC, cb4[3]);
      z0 = fmaf(y0 * __builtin_amdgcn_rcpf(1.f + __expf(-y0)), cw4[0], z0);
      z1 = fmaf(y1 * __builtin_amdgcn_rcpf(1.f + __expf(-y1)), cw4[1], z1);
      z2 = fmaf(y2 * __builtin_amdgcn_rcpf(1.f + __expf(-y2)), cw4[2], z2);
      z3 = fmaf(y3 * __builtin_amdgcn_rcpf(1.f + __expf(-y3)), cw4[3], z3);
    }
    float z = (z0 + z1) + (z2 + z3);
    z += __shfl_xor(z, 16); z += __shfl_xor(z, 32);

    // (8) depth-1 prefetch: next tile's pos + P words
    pf_pos(B);
    uint4 qra0, qra1, qca0, qca1;
    {
      const u32* pr = P + (size_t)B.ri * 64 + lg * 8;
      const u32* pc = P + (size_t)B.ci * 64 + 32 + lg * 8;
      qra0 = *(const uint4*)(pr); qra1 = *(const uint4*)(pr + 4);
      qca0 = *(const uint4*)(pc); qca1 = *(const uint4*)(pc + 4);
    }

    // (9) tanh -> scatter
    if (lg < 3) {
      float zc = fminf(fmaxf(z, -15.f), 15.f);
      float ez = __expf(2.f * zc);
      float inv = (ez - 1.f) * __builtin_amdgcn_rcpf(ez + 1.f);
      float dx = A.p0x - A.p1x, dy = A.p0y - A.p1y, dz = A.p0z - A.p1z;
      float nrm = sqrtf(fmaf(dx, dx, fmaf(dy, dy, dz * dz)));
      float sc  = cns * inv * __builtin_amdgcn_rcpf(fmaxf(nrm, 1e-8f));
      float d   = (lg == 0) ? dx : ((lg == 1) ? dy : dz);
      atomicAdd(out + (size_t)A.ri * 3 + lg, d * sc);
    }

    A = B;
    pra0 = qra0; pra1 = qra1;
    pca0 = qca0; pca1 = qca1;
  }
}

extern "C" void kernel_launch(void* const* d_in, const int* in_sizes, int n_in,
                              void* d_out, int out_size, void* d_ws, size_t ws_size,
                              hipStream_t stream) {
  const float* h         = (const float*)d_in[0];
  const float* pos       = (const float*)d_in[1];
  const float* edge_attr = (const float*)d_in[2];
  const float* dist      = (const float*)d_in[3];
  const float* te        = (const float*)d_in[4];
  const float* tW        = (const float*)d_in[5];
  const float* tb        = (const float*)d_in[6];
  const float* iW        = (const float*)d_in[7];
  const float* ib        = (const float*)d_in[8];
  const float* c1W       = (const float*)d_in[9];
  const float* c1b       = (const float*)d_in[10];
  const float* c2W       = (const float*)d_in[11];
  const float* cn        = (const float*)d_in[12];
  const int*   eidx      = (const int*)d_in[13];
  float* out = (float*)d_out;

  char* ws = (char*)d_ws;
  u32*   P      = (u32*)(ws);                    // 40000*256 B (fp8) = 10,240,000 B
  u16*   wPt    = (u16*)(ws + 10240000);         // 65,536 B
  u16*   wadWt  = (u16*)(ws + 10305536);         // 8,192 B (fp8)
  u16*   c1Wt   = (u16*)(ws + 10313728);         // 16,384 B (fp8)
  float* film   = (float*)(ws + 10330112);       // 1,024 B
  float* biasp  = (float*)(ws + 10331136);       // 512 B

  hipLaunchKernelGGL(prep_film_kernel,    dim3(1),    dim3(256), 0, stream, te, tW, tb, film);
  hipLaunchKernelGGL(prep_weights_kernel, dim3(177),  dim3(256), 0, stream,
                     iW, c1W, film, c1b, wPt, wadWt, c1Wt, biasp);
  hipLaunchKernelGGL(prep_P_kernel,       dim3(625),  dim3(256), 0, stream,
                     h, wPt, ib, pos, P, out);
  hipLaunchKernelGGL(edge_kernel,         dim3(GRID), dim3(512), 0, stream,
                     pos, edge_attr, dist, c2W, cn, eidx,
                     P, wadWt, c1Wt, biasp, out);
}

// Round 20
// 202.243 us; speedup vs baseline: 1.7963x; 1.7963x over previous
//
#include <hip/hip_runtime.h>
#include <hip/hip_bf16.h>
#include <stdint.h>

#define NN 40000
#define EE 640000
#define HD 128
#define TDIM 128
#define TB 128
#define NTILES (EE / TB)   // 5000
#define GRID 512           // persistent: 2 blocks/CU, 16 waves/CU

typedef short  s16x8 __attribute__((ext_vector_type(8)));
typedef float  f32x2 __attribute__((ext_vector_type(2)));
typedef float  f32x4 __attribute__((ext_vector_type(4)));
typedef unsigned short u16;
typedef unsigned int   u32;

#define PSCL 8.0f        // P stored x8 in fp8 e4m3
#define PDSC 0.125f
#define WSCALE 16.0f     // weights stored x16 in fp8; descale 1/16 after MFMA
#define WDSC 0.0625f

__device__ __forceinline__ u32 cvtpk(float lo, float hi) {
  u32 r; asm("v_cvt_pk_bf16_f32 %0, %1, %2" : "=v"(r) : "v"(lo), "v"(hi)); return r;
}
__device__ __forceinline__ u16 f2b(float f) {
  union { float f; u32 u; } x; x.f = f;
  u32 r = x.u + 0x7fffu + ((x.u >> 16) & 1u);
  return (u16)(r >> 16);
}

// ---- launch 1: FiLM params: film[0:128]=shift, film[128:256]=1+scale ----
__global__ void prep_film_kernel(const float* __restrict__ te, const float* __restrict__ tW,
                                 const float* __restrict__ tb, float* __restrict__ film) {
  __shared__ float s[TDIM];
  int t = threadIdx.x;
  if (t < TDIM) { float v = te[t]; s[t] = v * __builtin_amdgcn_rcpf(1.f + __expf(-v)); }
  __syncthreads();
  float acc = tb[t];
  #pragma unroll 8
  for (int k = 0; k < TDIM; ++k) acc = fmaf(s[k], tW[k * 256 + t], acc);
  film[t] = (t >= 128) ? (1.f + acc) : acc;
}

// ---- launch 2 (fused): wPt | wadWt(fp8) | c1Wt(fp8) | biasp ----
__global__ void prep_weights_kernel(const float* __restrict__ iW,
                                    const float* __restrict__ c1W,
                                    const float* __restrict__ film,
                                    const float* __restrict__ c1b,
                                    u16* __restrict__ wPt,
                                    u16* __restrict__ wadWt,
                                    u16* __restrict__ c1Wt,
                                    float* __restrict__ biasp) {
  int b = blockIdx.x, t = threadIdx.x;
  if (b < 128) {
    int idx = b * 256 + t;                 // < 32768
    int c = idx >> 7, k = idx & 127;
    wPt[idx] = f2b(iW[((c >> 7) * 128 + k) * HD + (c & 127)]);
  } else if (b < 144) {
    int pidx = (b - 128) * 256 + t;        // < 4096 fp8 pairs
    int idx = pidx * 2;
    int j0 = idx & 7, l15 = (idx >> 3) & 15, n = (idx >> 7) & 7, lg = (idx >> 10) & 3, ks = idx >> 12;
    int row = n * 16 + l15;
    int k0 = ks * 32 + lg * 8 + j0;
    float v0 = WSCALE * iW[(256 + k0) * HD + row];
    float v1 = WSCALE * iW[(256 + k0 + 1) * HD + row];
    u32 p = __builtin_amdgcn_cvt_pk_fp8_f32(v0, v1, 0, false);
    wadWt[pidx] = (u16)p;
  } else if (b < 176) {
    int pidx = (b - 144) * 256 + t;        // < 8192 fp8 pairs
    int idx = pidx * 2;
    int j0 = idx & 7, l15 = (idx >> 3) & 15, n = (idx >> 7) & 7, lg = (idx >> 10) & 3, kq = idx >> 12;
    int row = n * 16 + l15;
    int ch0 = (kq * 2 + (j0 >> 2)) * 16 + lg * 4 + (j0 & 3);
    int ch1 = (kq * 2 + ((j0 + 1) >> 2)) * 16 + lg * 4 + ((j0 + 1) & 3);
    float v0 = WSCALE * film[128 + ch0] * c1W[ch0 * HD + row];
    float v1 = WSCALE * film[128 + ch1] * c1W[ch1 * HD + row];
    u32 p = __builtin_amdgcn_cvt_pk_fp8_f32(v0, v1, 0, false);
    c1Wt[pidx] = (u16)p;
  } else if (t < 128) {
    float acc = c1b[t];
    #pragma unroll 8
    for (int k = 0; k < 128; ++k) acc = fmaf(film[k], c1W[k * HD + t], acc);
    biasp[t] = acc;
  }
}

// ---- launch 3: P[node] = 64 u32 words of fp8 (x8), fragment-permuted; + pos copy ----
__global__ __launch_bounds__(256) void prep_P_kernel(const float* __restrict__ h,
                                                     const u16* __restrict__ wPt,
                                                     const float* __restrict__ ib,
                                                     const float* __restrict__ pos,
                                                     u32* __restrict__ P,
                                                     float* __restrict__ out) {
  __shared__ u16 sWp[256][136];
  __shared__ float sib[HD];
  int t = threadIdx.x;
  {
    int ci = blockIdx.x * 192 + t;
    if (t < 192) out[ci] = pos[ci];
  }
  if (t < 128) sib[t] = ib[t];
  {
    const u16* src = wPt + t * 128;
    #pragma unroll
    for (int i = 0; i < 16; ++i)
      *(uint4*)&sWp[t][i * 8] = *(const uint4*)(src + i * 8);
  }
  int wave = t >> 6, lane = t & 63, l15 = lane & 15, lg = lane >> 4;
  int node = blockIdx.x * 64 + wave * 16 + l15;
  uint4 hb[4];
  const float* hr = h + (size_t)node * HD + lg * 8;
  #pragma unroll
  for (int c = 0; c < 4; ++c) {
    float4 a = *(const float4*)(hr + c * 32);
    float4 b = *(const float4*)(hr + c * 32 + 4);
    hb[c].x = cvtpk(a.x, a.y); hb[c].y = cvtpk(a.z, a.w);
    hb[c].z = cvtpk(b.x, b.y); hb[c].w = cvtpk(b.z, b.w);
  }
  __syncthreads();
  f32x4 acc[16];
  #pragma unroll
  for (int n = 0; n < 16; ++n) acc[n] = (f32x4){0.f, 0.f, 0.f, 0.f};
  #pragma unroll
  for (int c = 0; c < 4; ++c) {
    s16x8 bF = *(const s16x8*)&hb[c];
    #pragma unroll
    for (int n = 0; n < 16; ++n) {
      s16x8 aF = *(const s16x8*)&sWp[n * 16 + l15][c * 32 + lg * 8];
      acc[n] = __builtin_amdgcn_mfma_f32_16x16x32_bf16(aF, bF, acc[n], 0, 0, 0);
    }
  }
  u32* dst = P + (size_t)node * 64;
  #pragma unroll
  for (int n = 0; n < 16; ++n) {
    int side = n >> 3;
    int cb = (n & 7) * 16 + lg * 4;
    float a0 = acc[n][0], a1 = acc[n][1], a2 = acc[n][2], a3 = acc[n][3];
    if (side == 0) { a0 += sib[cb]; a1 += sib[cb + 1]; a2 += sib[cb + 2]; a3 += sib[cb + 3]; }
    u32 w = __builtin_amdgcn_cvt_pk_fp8_f32(PSCL * a0, PSCL * a1, 0, false);
    w = __builtin_amdgcn_cvt_pk_fp8_f32(PSCL * a2, PSCL * a3, w, true);
    dst[side * 32 + lg * 8 + (n & 7)] = w;
  }
}

// ---- small prefetch state ----
struct PfS {
  int ri, ci;
  float4 a0, a1, d0, d1;
  float p0x, p0y, p0z, p1x, p1y, p1z;
};

// ---- launch 4: persistent fused edge kernel (fp8 weights + fp8 P, reg cap 85) ----
__global__ __launch_bounds__(512, 3) void edge_kernel(
    const float* __restrict__ pos,
    const float* __restrict__ edge_attr,
    const float* __restrict__ dist,
    const float* __restrict__ c2w,
    const float* __restrict__ cn_scale,
    const int*   __restrict__ eidx,
    const u32*   __restrict__ P,       // [N][64] u32 of fp8(x8), fragment-permuted
    const u16*   __restrict__ wadWt,   // 8 KB fp8 GEMM1 weights (x16)
    const u16*   __restrict__ c1Wt,    // 16 KB fp8 GEMM2 weights (x16, k-permuted)
    const float* __restrict__ biasp,   // [128]
    float*       __restrict__ out)
{
  __shared__ u16   sW1[4096];    // 8 KB fp8
  __shared__ u16   sW2[8192];    // 16 KB fp8
  __shared__ float sC1b[HD];
  __shared__ float sC2w[HD];

  const int t    = threadIdx.x;
  const int lane = t & 63;
  const int wave = t >> 6;        // 0..7
  const int l15  = lane & 15;
  const int lg   = lane >> 4;
  const int wv   = wave * 16 + l15;   // edge offset in tile, 0..127

  if (t < HD) { sC1b[t] = biasp[t]; sC2w[t] = c2w[t]; }
  {
    const uint4* s1 = (const uint4*)wadWt;   // 512 uint4
    uint4* d1 = (uint4*)sW1;
    if (t < 512) d1[t] = s1[t];
    const uint4* s2 = (const uint4*)c1Wt;    // 1024 uint4
    uint4* d2 = (uint4*)sW2;
    #pragma unroll
    for (int i = 0; i < 2; ++i) d2[t + i * 512] = s2[t + i * 512];
  }

  const float cns = cn_scale[0];
  const int bb8 = lg * 1024 + l15 * 8;   // byte base within each 4KB fp8 k-panel

  auto pf_idx_ad = [&](PfS& p, int tile) {
    int e = tile * TB + wv;
    p.ri = eidx[e];
    p.ci = eidx[EE + e];
    const float* pa = edge_attr + (size_t)e * 32 + lg * 8;
    const float* pd = dist      + (size_t)e * 32 + lg * 8;
    p.a0 = *(const float4*)(pa); p.a1 = *(const float4*)(pa + 4);
    p.d0 = *(const float4*)(pd); p.d1 = *(const float4*)(pd + 4);
  };
  auto pf_pos = [&](PfS& p) {
    p.p0x = pos[p.ri * 3 + 0]; p.p0y = pos[p.ri * 3 + 1]; p.p0z = pos[p.ri * 3 + 2];
    p.p1x = pos[p.ci * 3 + 0]; p.p1y = pos[p.ci * 3 + 1]; p.p1z = pos[p.ci * 3 + 2];
  };

  PfS A, B;
  pf_idx_ad(A, blockIdx.x);
  pf_pos(A);

  // prologue: P gathers (fp8: 2 uint4 per side)
  uint4 pra0, pra1, pca0, pca1;
  {
    const u32* pr = P + (size_t)A.ri * 64 + lg * 8;
    const u32* pc = P + (size_t)A.ci * 64 + 32 + lg * 8;
    pra0 = *(const uint4*)(pr); pra1 = *(const uint4*)(pr + 4);
    pca0 = *(const uint4*)(pc); pca1 = *(const uint4*)(pc + 4);
  }

  __syncthreads();   // only barrier: weights + consts visible

  for (int tile = blockIdx.x; tile < NTILES; tile += GRID) {
    int tn = tile + GRID; if (tn >= NTILES) tn = tile;

    // (1) next tile's independent loads — in flight across this tile
    pf_idx_ad(B, tn);

    // (2) pack features to fp8 (x1; weights carry x16)
    long ef0, ef1;
    {
      u32 a0 = __builtin_amdgcn_cvt_pk_fp8_f32(A.a0.x, A.a0.y, 0, false);
      a0 = __builtin_amdgcn_cvt_pk_fp8_f32(A.a0.z, A.a0.w, a0, true);
      u32 a1 = __builtin_amdgcn_cvt_pk_fp8_f32(A.a1.x, A.a1.y, 0, false);
      a1 = __builtin_amdgcn_cvt_pk_fp8_f32(A.a1.z, A.a1.w, a1, true);
      u32 d0 = __builtin_amdgcn_cvt_pk_fp8_f32(A.d0.x, A.d0.y, 0, false);
      d0 = __builtin_amdgcn_cvt_pk_fp8_f32(A.d0.z, A.d0.w, d0, true);
      u32 d1 = __builtin_amdgcn_cvt_pk_fp8_f32(A.d1.x, A.d1.y, 0, false);
      d1 = __builtin_amdgcn_cvt_pk_fp8_f32(A.d1.z, A.d1.w, d1, true);
      ef0 = (long)(((unsigned long long)a1 << 32) | a0);
      ef1 = (long)(((unsigned long long)d1 << 32) | d0);
    }

    // (3) GEMM1 (fp8): Q = [attr|dist] @ iW_ad, immediate-offset ds_read_b64
    f32x4 acc[8];
    #pragma unroll
    for (int n = 0; n < 8; ++n) acc[n] = (f32x4){0.f, 0.f, 0.f, 0.f};
    #pragma unroll
    for (int ks = 0; ks < 2; ++ks) {
      long bF = (ks == 0) ? ef0 : ef1;
      #pragma unroll
      for (int n = 0; n < 8; ++n) {
        long aF = *(const long*)((const char*)sW1 + ks * 4096 + bb8 + n * 128);
        acc[n] = __builtin_amdgcn_mfma_f32_16x16x32_fp8_fp8(aF, bF, acc[n], 0, 0, 0);
      }
    }

    // (4) x = Q/16 + (P_r + P_c)/8; LN stats with 4-way partial accumulators
    float x[8][4];
    float s0=0.f,s1=0.f,s2=0.f,s3=0.f, q0=0.f,q1=0.f,q2=0.f,q3=0.f;
    #pragma unroll
    for (int i = 0; i < 2; ++i) {
      uint4 wa = (i == 0) ? pra0 : pra1;
      uint4 wc = (i == 0) ? pca0 : pca1;
      #pragma unroll
      for (int k = 0; k < 4; ++k) {
        int n = i * 4 + k;
        u32 aw = (k == 0) ? wa.x : (k == 1) ? wa.y : (k == 2) ? wa.z : wa.w;
        u32 cw = (k == 0) ? wc.x : (k == 1) ? wc.y : (k == 2) ? wc.z : wc.w;
        f32x2 a01 = __builtin_amdgcn_cvt_pk_f32_fp8(aw, false);
        f32x2 a23 = __builtin_amdgcn_cvt_pk_f32_fp8(aw, true);
        f32x2 c01 = __builtin_amdgcn_cvt_pk_f32_fp8(cw, false);
        f32x2 c23 = __builtin_amdgcn_cvt_pk_f32_fp8(cw, true);
        float v0 = fmaf(acc[n][0], WDSC, (a01[0] + c01[0]) * PDSC);
        float v1 = fmaf(acc[n][1], WDSC, (a01[1] + c01[1]) * PDSC);
        float v2 = fmaf(acc[n][2], WDSC, (a23[0] + c23[0]) * PDSC);
        float v3 = fmaf(acc[n][3], WDSC, (a23[1] + c23[1]) * PDSC);
        x[n][0] = v0; x[n][1] = v1; x[n][2] = v2; x[n][3] = v3;
        s0 += v0; s1 += v1; s2 += v2; s3 += v3;
        q0 = fmaf(v0,v0,q0); q1 = fmaf(v1,v1,q1);
        q2 = fmaf(v2,v2,q2); q3 = fmaf(v3,v3,q3);
      }
    }
    float sum = (s0 + s1) + (s2 + s3);
    float sq  = (q0 + q1) + (q2 + q3);
    sum += __shfl_xor(sum, 16); sum += __shfl_xor(sum, 32);
    sq  += __shfl_xor(sq,  16); sq  += __shfl_xor(sq,  32);
    float mean = sum * (1.f / 128.f);
    float var  = sq  * (1.f / 128.f) - mean * mean;
    float LA = rsqrtf(var + 1e-6f);
    float LB = -mean * LA;

    // (5) x-hat -> fp8 words (GEMM2 B-operand, k-permuted)
    u32 xp[8];
    #pragma unroll
    for (int n = 0; n < 8; ++n) {
      float y0 = fmaf(x[n][0], LA, LB);
      float y1 = fmaf(x[n][1], LA, LB);
      float y2 = fmaf(x[n][2], LA, LB);
      float y3 = fmaf(x[n][3], LA, LB);
      u32 w = __builtin_amdgcn_cvt_pk_fp8_f32(y0, y1, 0, false);
      w = __builtin_amdgcn_cvt_pk_fp8_f32(y2, y3, w, true);
      xp[n] = w;
    }

    // (6) GEMM2 (fp8): reuse acc; B from registers, A via immediate-offset ds_read_b64
    #pragma unroll
    for (int n = 0; n < 8; ++n) acc[n] = (f32x4){0.f, 0.f, 0.f, 0.f};
    #pragma unroll
    for (int kq = 0; kq < 4; ++kq) {
      long xF = (long)(((unsigned long long)xp[2*kq+1] << 32) | xp[2*kq]);
      #pragma unroll
      for (int n = 0; n < 8; ++n) {
        long aF = *(const long*)((const char*)sW2 + kq * 4096 + bb8 + n * 128);
        acc[n] = __builtin_amdgcn_mfma_f32_16x16x32_fp8_fp8(aF, xF, acc[n], 0, 0, 0);
      }
    }

    // (7) silu -> dot(c2W) with 4-way partial chains (descale 1/16)
    float z0=0.f, z1=0.f, z2=0.f, z3=0.f;
    #pragma unroll
    for (int n = 0; n < 8; ++n) {
      int cb = n * 16 + lg * 4;
      f32x4 cb4 = *(const f32x4*)&sC1b[cb];
      f32x4 cw4 = *(const f32x4*)&sC2w[cb];
      float y0 = fmaf(acc[n][0], WDSC, cb4[0]);
      float y1 = fmaf(acc[n][1], WDSC, cb4[1]);
      float y2 = fmaf(acc[n][2], WDSC, cb4[2]);
      float y3 = fmaf(acc[n][3], WDSC, cb4[3]);
      z0 = fmaf(y0 * __builtin_amdgcn_rcpf(1.f + __expf(-y0)), cw4[0], z0);
      z1 = fmaf(y1 * __builtin_amdgcn_rcpf(1.f + __expf(-y1)), cw4[1], z1);
      z2 = fmaf(y2 * __builtin_amdgcn_rcpf(1.f + __expf(-y2)), cw4[2], z2);
      z3 = fmaf(y3 * __builtin_amdgcn_rcpf(1.f + __expf(-y3)), cw4[3], z3);
    }
    float z = (z0 + z1) + (z2 + z3);
    z += __shfl_xor(z, 16); z += __shfl_xor(z, 32);

    // (8) depth-1 prefetch: next tile's pos + P words
    pf_pos(B);
    uint4 qra0, qra1, qca0, qca1;
    {
      const u32* pr = P + (size_t)B.ri * 64 + lg * 8;
      const u32* pc = P + (size_t)B.ci * 64 + 32 + lg * 8;
      qra0 = *(const uint4*)(pr); qra1 = *(const uint4*)(pr + 4);
      qca0 = *(const uint4*)(pc); qca1 = *(const uint4*)(pc + 4);
    }

    // (9) tanh -> scatter
    if (lg < 3) {
      float zc = fminf(fmaxf(z, -15.f), 15.f);
      float ez = __expf(2.f * zc);
      float inv = (ez - 1.f) * __builtin_amdgcn_rcpf(ez + 1.f);
      float dx = A.p0x - A.p1x, dy = A.p0y - A.p1y, dz = A.p0z - A.p1z;
      float nrm = sqrtf(fmaf(dx, dx, fmaf(dy, dy, dz * dz)));
      float sc  = cns * inv * __builtin_amdgcn_rcpf(fmaxf(nrm, 1e-8f));
      float d   = (lg == 0) ? dx : ((lg == 1) ? dy : dz);
      atomicAdd(out + (size_t)A.ri * 3 + lg, d * sc);
    }

    A = B;
    pra0 = qra0; pra1 = qra1;
    pca0 = qca0; pca1 = qca1;
  }
}

extern "C" void kernel_launch(void* const* d_in, const int* in_sizes, int n_in,
                              void* d_out, int out_size, void* d_ws, size_t ws_size,
                              hipStream_t stream) {
  const float* h         = (const float*)d_in[0];
  const float* pos       = (const float*)d_in[1];
  const float* edge_attr = (const float*)d_in[2];
  const float* dist      = (const float*)d_in[3];
  const float* te        = (const float*)d_in[4];
  const float* tW        = (const float*)d_in[5];
  const float* tb        = (const float*)d_in[6];
  const float* iW        = (const float*)d_in[7];
  const float* ib        = (const float*)d_in[8];
  const float* c1W       = (const float*)d_in[9];
  const float* c1b       = (const float*)d_in[10];
  const float* c2W       = (const float*)d_in[11];
  const float* cn        = (const float*)d_in[12];
  const int*   eidx      = (const int*)d_in[13];
  float* out = (float*)d_out;

  char* ws = (char*)d_ws;
  u32*   P      = (u32*)(ws);                    // 40000*256 B (fp8) = 10,240,000 B
  u16*   wPt    = (u16*)(ws + 10240000);         // 65,536 B
  u16*   wadWt  = (u16*)(ws + 10305536);         // 8,192 B (fp8)
  u16*   c1Wt   = (u16*)(ws + 10313728);         // 16,384 B (fp8)
  float* film   = (float*)(ws + 10330112);       // 1,024 B
  float* biasp  = (float*)(ws + 10331136);       // 512 B

  hipLaunchKernelGGL(prep_film_kernel,    dim3(1),    dim3(256), 0, stream, te, tW, tb, film);
  hipLaunchKernelGGL(prep_weights_kernel, dim3(177),  dim3(256), 0, stream,
                     iW, c1W, film, c1b, wPt, wadWt, c1Wt, biasp);
  hipLaunchKernelGGL(prep_P_kernel,       dim3(625),  dim3(256), 0, stream,
                     h, wPt, ib, pos, P, out);
  hipLaunchKernelGGL(edge_kernel,         dim3(GRID), dim3(512), 0, stream,
                     pos, edge_attr, dist, c2W, cn, eidx,
                     P, wadWt, c1Wt, biasp, out);
}

// Round 21
// 99.472 us; speedup vs baseline: 3.6521x; 2.0332x over previous
//
#include <hip/hip_runtime.h>
#include <hip/hip_bf16.h>
#include <stdint.h>

#define NN 40000
#define EE 640000
#define HD 128
#define TDIM 128
#define TB 128
#define NTILES (EE / TB)   // 5000
#define GRID 512           // persistent: 2 blocks/CU, 16 waves/CU

typedef short  s16x8 __attribute__((ext_vector_type(8)));
typedef float  f32x2 __attribute__((ext_vector_type(2)));
typedef float  f32x4 __attribute__((ext_vector_type(4)));
typedef unsigned int u32x4 __attribute__((ext_vector_type(4)));
typedef unsigned short u16;
typedef unsigned int   u32;

#define PSCL 8.0f        // P stored x8 in fp8 e4m3
#define PDSC 0.125f      // descale on unpack

__device__ __forceinline__ u32 cvtpk(float lo, float hi) {
  u32 r; asm("v_cvt_pk_bf16_f32 %0, %1, %2" : "=v"(r) : "v"(lo), "v"(hi)); return r;
}
__device__ __forceinline__ u16 f2b(float f) {
  union { float f; u32 u; } x; x.f = f;
  u32 r = x.u + 0x7fffu + ((x.u >> 16) & 1u);
  return (u16)(r >> 16);
}

// ---- launch 1: FiLM params: film[0:128]=shift, film[128:256]=1+scale ----
__global__ void prep_film_kernel(const float* __restrict__ te, const float* __restrict__ tW,
                                 const float* __restrict__ tb, float* __restrict__ film) {
  __shared__ float s[TDIM];
  int t = threadIdx.x;
  if (t < TDIM) { float v = te[t]; s[t] = v * __builtin_amdgcn_rcpf(1.f + __expf(-v)); }
  __syncthreads();
  float acc = tb[t];
  #pragma unroll 8
  for (int k = 0; k < TDIM; ++k) acc = fmaf(s[k], tW[k * 256 + t], acc);
  film[t] = (t >= 128) ? (1.f + acc) : acc;
}

// ---- launch 2 (fused): wPt | wadWt | c1Wt | biasp, partitioned by blockIdx ----
__global__ void prep_weights_kernel(const float* __restrict__ iW,
                                    const float* __restrict__ c1W,
                                    const float* __restrict__ film,
                                    const float* __restrict__ c1b,
                                    u16* __restrict__ wPt,
                                    u16* __restrict__ wadWt,
                                    u16* __restrict__ c1Wt,
                                    float* __restrict__ biasp) {
  int b = blockIdx.x, t = threadIdx.x;
  if (b < 128) {
    int idx = b * 256 + t;                 // < 32768
    int c = idx >> 7, k = idx & 127;
    wPt[idx] = f2b(iW[((c >> 7) * 128 + k) * HD + (c & 127)]);
  } else if (b < 160) {
    int idx = (b - 128) * 256 + t;         // < 8192
    int j = idx & 7, l15 = (idx >> 3) & 15, n = (idx >> 7) & 7, lg = (idx >> 10) & 3, ks = idx >> 12;
    int row = n * 16 + l15;
    int k = ks * 32 + lg * 8 + j;
    wadWt[idx] = f2b(iW[(256 + k) * HD + row]);
  } else if (b < 224) {
    int idx = (b - 160) * 256 + t;         // < 16384
    int j = idx & 7, l15 = (idx >> 3) & 15, n = (idx >> 7) & 7, lg = (idx >> 10) & 3, kq = idx >> 12;
    int row = n * 16 + l15;
    int ch = (kq * 2 + (j >> 2)) * 16 + lg * 4 + (j & 3);
    c1Wt[idx] = f2b(film[128 + ch] * c1W[ch * HD + row]);
  } else if (t < 128) {
    float acc = c1b[t];
    #pragma unroll 8
    for (int k = 0; k < 128; ++k) acc = fmaf(film[k], c1W[k * HD + t], acc);
    biasp[t] = acc;
  }
}

// ---- launch 3: P[node] = 64 u32 words of fp8 (x8), fragment-permuted; + pos copy ----
//      word(side,lg,n) = side*32 + lg*8 + n holds channels {n*16+lg*4 + 0..3} of that side
__global__ __launch_bounds__(256) void prep_P_kernel(const float* __restrict__ h,
                                                     const u16* __restrict__ wPt,
                                                     const float* __restrict__ ib,
                                                     const float* __restrict__ pos,
                                                     u32* __restrict__ P,
                                                     float* __restrict__ out) {
  __shared__ u16 sWp[256][136];
  __shared__ float sib[HD];
  int t = threadIdx.x;
  {
    int ci = blockIdx.x * 192 + t;
    if (t < 192) out[ci] = pos[ci];
  }
  if (t < 128) sib[t] = ib[t];
  {
    const u16* src = wPt + t * 128;
    #pragma unroll
    for (int i = 0; i < 16; ++i)
      *(uint4*)&sWp[t][i * 8] = *(const uint4*)(src + i * 8);
  }
  int wave = t >> 6, lane = t & 63, l15 = lane & 15, lg = lane >> 4;
  int node = blockIdx.x * 64 + wave * 16 + l15;
  uint4 hb[4];
  const float* hr = h + (size_t)node * HD + lg * 8;
  #pragma unroll
  for (int c = 0; c < 4; ++c) {
    float4 a = *(const float4*)(hr + c * 32);
    float4 b = *(const float4*)(hr + c * 32 + 4);
    hb[c].x = cvtpk(a.x, a.y); hb[c].y = cvtpk(a.z, a.w);
    hb[c].z = cvtpk(b.x, b.y); hb[c].w = cvtpk(b.z, b.w);
  }
  __syncthreads();
  f32x4 acc[16];
  #pragma unroll
  for (int n = 0; n < 16; ++n) acc[n] = (f32x4){0.f, 0.f, 0.f, 0.f};
  #pragma unroll
  for (int c = 0; c < 4; ++c) {
    s16x8 bF = *(const s16x8*)&hb[c];
    #pragma unroll
    for (int n = 0; n < 16; ++n) {
      s16x8 aF = *(const s16x8*)&sWp[n * 16 + l15][c * 32 + lg * 8];
      acc[n] = __builtin_amdgcn_mfma_f32_16x16x32_bf16(aF, bF, acc[n], 0, 0, 0);
    }
  }
  u32* dst = P + (size_t)node * 64;
  #pragma unroll
  for (int n = 0; n < 16; ++n) {
    int side = n >> 3;
    int cb = (n & 7) * 16 + lg * 4;
    float a0 = acc[n][0], a1 = acc[n][1], a2 = acc[n][2], a3 = acc[n][3];
    if (side == 0) { a0 += sib[cb]; a1 += sib[cb + 1]; a2 += sib[cb + 2]; a3 += sib[cb + 3]; }
    u32 w = __builtin_amdgcn_cvt_pk_fp8_f32(PSCL * a0, PSCL * a1, 0, false);
    w = __builtin_amdgcn_cvt_pk_fp8_f32(PSCL * a2, PSCL * a3, w, true);
    dst[side * 32 + lg * 8 + (n & 7)] = w;
  }
}

// ---- small prefetch state ----
struct PfS {
  int ri, ci;
  float4 a0, a1, d0, d1;
  float p0x, p0y, p0z, p1x, p1y, p1z;
};

// ---- launch 4: persistent fused edge kernel (R18 champion: fp8 P, bf16 weights) ----
__global__ __launch_bounds__(512, 4) void edge_kernel(
    const float* __restrict__ pos,
    const float* __restrict__ edge_attr,
    const float* __restrict__ dist,
    const float* __restrict__ c2w,
    const float* __restrict__ cn_scale,
    const int*   __restrict__ eidx,
    const u32*   __restrict__ P,       // [N][64] u32 of fp8(x8), fragment-permuted
    const u16*   __restrict__ wadWt,   // [8192]  fragment-ordered GEMM1 weights
    const u16*   __restrict__ c1Wt,    // [16384] fragment-ordered, k-permuted GEMM2 weights
    const float* __restrict__ biasp,   // [128]
    float*       __restrict__ out)
{
  __shared__ u16   sW1[8192];    // 16 KB
  __shared__ u16   sW2[16384];   // 32 KB
  __shared__ float sC1b[HD];
  __shared__ float sC2w[HD];

  const int t    = threadIdx.x;
  const int lane = t & 63;
  const int wave = t >> 6;        // 0..7
  const int l15  = lane & 15;
  const int lg   = lane >> 4;
  const int wv   = wave * 16 + l15;   // edge offset in tile, 0..127

  if (t < HD) { sC1b[t] = biasp[t]; sC2w[t] = c2w[t]; }
  {
    const uint4* s1 = (const uint4*)wadWt;   // 1024 uint4
    uint4* d1 = (uint4*)sW1;
    #pragma unroll
    for (int i = 0; i < 2; ++i) d1[t + i * 512] = s1[t + i * 512];
    const uint4* s2 = (const uint4*)c1Wt;    // 2048 uint4
    uint4* d2 = (uint4*)sW2;
    #pragma unroll
    for (int i = 0; i < 4; ++i) d2[t + i * 512] = s2[t + i * 512];
  }

  const float cns = cn_scale[0];
  const int bbase = lg * 2048 + l15 * 16;   // byte base within each 8KB k-panel

  auto pf_idx_ad = [&](PfS& p, int tile) {
    int e = tile * TB + wv;
    p.ri = eidx[e];
    p.ci = eidx[EE + e];
    const float* pa = edge_attr + (size_t)e * 32 + lg * 8;
    const float* pd = dist      + (size_t)e * 32 + lg * 8;
    p.a0 = *(const float4*)(pa); p.a1 = *(const float4*)(pa + 4);
    p.d0 = *(const float4*)(pd); p.d1 = *(const float4*)(pd + 4);
  };
  auto pf_pos = [&](PfS& p) {
    p.p0x = pos[p.ri * 3 + 0]; p.p0y = pos[p.ri * 3 + 1]; p.p0z = pos[p.ri * 3 + 2];
    p.p1x = pos[p.ci * 3 + 0]; p.p1y = pos[p.ci * 3 + 1]; p.p1z = pos[p.ci * 3 + 2];
  };

  PfS A, B;
  pf_idx_ad(A, blockIdx.x);
  pf_pos(A);

  // prologue: P gathers (fp8: 2 uint4 per side)
  uint4 pra0, pra1, pca0, pca1;
  {
    const u32* pr = P + (size_t)A.ri * 64 + lg * 8;
    const u32* pc = P + (size_t)A.ci * 64 + 32 + lg * 8;
    pra0 = *(const uint4*)(pr); pra1 = *(const uint4*)(pr + 4);
    pca0 = *(const uint4*)(pc); pca1 = *(const uint4*)(pc + 4);
  }

  __syncthreads();   // only barrier: weights + consts visible

  for (int tile = blockIdx.x; tile < NTILES; tile += GRID) {
    int tn = tile + GRID; if (tn >= NTILES) tn = tile;

    // (1) next tile's independent loads — in flight across this tile
    pf_idx_ad(B, tn);

    // (2) GEMM1: Q = [attr|dist] @ iW_ad, all-immediate-offset LDS reads
    uint4 ef0, ef1;
    ef0.x = cvtpk(A.a0.x, A.a0.y); ef0.y = cvtpk(A.a0.z, A.a0.w);
    ef0.z = cvtpk(A.a1.x, A.a1.y); ef0.w = cvtpk(A.a1.z, A.a1.w);
    ef1.x = cvtpk(A.d0.x, A.d0.y); ef1.y = cvtpk(A.d0.z, A.d0.w);
    ef1.z = cvtpk(A.d1.x, A.d1.y); ef1.w = cvtpk(A.d1.z, A.d1.w);

    f32x4 acc[8];
    #pragma unroll
    for (int n = 0; n < 8; ++n) acc[n] = (f32x4){0.f, 0.f, 0.f, 0.f};
    #pragma unroll
    for (int ks = 0; ks < 2; ++ks) {
      s16x8 bF = (ks == 0) ? *(const s16x8*)&ef0 : *(const s16x8*)&ef1;
      #pragma unroll
      for (int n = 0; n < 8; ++n) {
        s16x8 aF = *(const s16x8*)((const char*)sW1 + ks * 8192 + bbase + n * 256);
        acc[n] = __builtin_amdgcn_mfma_f32_16x16x32_bf16(aF, bF, acc[n], 0, 0, 0);
      }
    }

    // (3) x = Q + (P_r + P_c)/8; LN stats with 4-way partial accumulators
    //     fp8 word n holds exactly channels of acc[n]
    float x[8][4];
    float s0=0.f,s1=0.f,s2=0.f,s3=0.f, q0=0.f,q1=0.f,q2=0.f,q3=0.f;
    #pragma unroll
    for (int i = 0; i < 2; ++i) {
      uint4 wa = (i == 0) ? pra0 : pra1;
      uint4 wc = (i == 0) ? pca0 : pca1;
      #pragma unroll
      for (int k = 0; k < 4; ++k) {
        int n = i * 4 + k;
        u32 aw = (k == 0) ? wa.x : (k == 1) ? wa.y : (k == 2) ? wa.z : wa.w;
        u32 cw = (k == 0) ? wc.x : (k == 1) ? wc.y : (k == 2) ? wc.z : wc.w;
        f32x2 a01 = __builtin_amdgcn_cvt_pk_f32_fp8(aw, false);
        f32x2 a23 = __builtin_amdgcn_cvt_pk_f32_fp8(aw, true);
        f32x2 c01 = __builtin_amdgcn_cvt_pk_f32_fp8(cw, false);
        f32x2 c23 = __builtin_amdgcn_cvt_pk_f32_fp8(cw, true);
        float v0 = fmaf(a01[0] + c01[0], PDSC, acc[n][0]);
        float v1 = fmaf(a01[1] + c01[1], PDSC, acc[n][1]);
        float v2 = fmaf(a23[0] + c23[0], PDSC, acc[n][2]);
        float v3 = fmaf(a23[1] + c23[1], PDSC, acc[n][3]);
        x[n][0] = v0; x[n][1] = v1; x[n][2] = v2; x[n][3] = v3;
        s0 += v0; s1 += v1; s2 += v2; s3 += v3;
        q0 = fmaf(v0,v0,q0); q1 = fmaf(v1,v1,q1);
        q2 = fmaf(v2,v2,q2); q3 = fmaf(v3,v3,q3);
      }
    }
    float sum = (s0 + s1) + (s2 + s3);
    float sq  = (q0 + q1) + (q2 + q3);
    sum += __shfl_xor(sum, 16); sum += __shfl_xor(sum, 32);
    sq  += __shfl_xor(sq,  16); sq  += __shfl_xor(sq,  32);
    float mean = sum * (1.f / 128.f);
    float var  = sq  * (1.f / 128.f) - mean * mean;
    float LA = rsqrtf(var + 1e-6f);
    float LB = -mean * LA;

    union { uint2 u2[8]; u32 w[16]; } xb;
    #pragma unroll
    for (int n = 0; n < 8; ++n) {
      float y0 = fmaf(x[n][0], LA, LB);
      float y1 = fmaf(x[n][1], LA, LB);
      float y2 = fmaf(x[n][2], LA, LB);
      float y3 = fmaf(x[n][3], LA, LB);
      xb.u2[n].x = cvtpk(y0, y1);
      xb.u2[n].y = cvtpk(y2, y3);
    }

    // (4) GEMM2: reuse acc (AGPR overlap); B from registers, A via LDS
    #pragma unroll
    for (int n = 0; n < 8; ++n) acc[n] = (f32x4){0.f, 0.f, 0.f, 0.f};
    #pragma unroll
    for (int kq = 0; kq < 4; ++kq) {
      u32x4 xw = { xb.w[4*kq], xb.w[4*kq+1], xb.w[4*kq+2], xb.w[4*kq+3] };
      s16x8 xF = __builtin_bit_cast(s16x8, xw);
      #pragma unroll
      for (int n = 0; n < 8; ++n) {
        s16x8 aF = *(const s16x8*)((const char*)sW2 + kq * 8192 + bbase + n * 256);
        acc[n] = __builtin_amdgcn_mfma_f32_16x16x32_bf16(aF, xF, acc[n], 0, 0, 0);
      }
    }

    // (5) silu -> dot(c2W) with 4-way partial chains
    float z0=0.f, z1=0.f, z2=0.f, z3=0.f;
    #pragma unroll
    for (int n = 0; n < 8; ++n) {
      int cb = n * 16 + lg * 4;
      f32x4 cb4 = *(const f32x4*)&sC1b[cb];
      f32x4 cw4 = *(const f32x4*)&sC2w[cb];
      float y0 = acc[n][0] + cb4[0];
      float y1 = acc[n][1] + cb4[1];
      float y2 = acc[n][2] + cb4[2];
      float y3 = acc[n][3] + cb4[3];
      z0 = fmaf(y0 * __builtin_amdgcn_rcpf(1.f + __expf(-y0)), cw4[0], z0);
      z1 = fmaf(y1 * __builtin_amdgcn_rcpf(1.f + __expf(-y1)), cw4[1], z1);
      z2 = fmaf(y2 * __builtin_amdgcn_rcpf(1.f + __expf(-y2)), cw4[2], z2);
      z3 = fmaf(y3 * __builtin_amdgcn_rcpf(1.f + __expf(-y3)), cw4[3], z3);
    }
    float z = (z0 + z1) + (z2 + z3);
    z += __shfl_xor(z, 16); z += __shfl_xor(z, 32);

    // (6) depth-1 prefetch: next tile's pos + P words
    pf_pos(B);
    uint4 qra0, qra1, qca0, qca1;
    {
      const u32* pr = P + (size_t)B.ri * 64 + lg * 8;
      const u32* pc = P + (size_t)B.ci * 64 + 32 + lg * 8;
      qra0 = *(const uint4*)(pr); qra1 = *(const uint4*)(pr + 4);
      qca0 = *(const uint4*)(pc); qca1 = *(const uint4*)(pc + 4);
    }

    // (7) tanh -> scatter
    if (lg < 3) {
      float zc = fminf(fmaxf(z, -15.f), 15.f);
      float ez = __expf(2.f * zc);
      float inv = (ez - 1.f) * __builtin_amdgcn_rcpf(ez + 1.f);
      float dx = A.p0x - A.p1x, dy = A.p0y - A.p1y, dz = A.p0z - A.p1z;
      float nrm = sqrtf(fmaf(dx, dx, fmaf(dy, dy, dz * dz)));
      float sc  = cns * inv * __builtin_amdgcn_rcpf(fmaxf(nrm, 1e-8f));
      float d   = (lg == 0) ? dx : ((lg == 1) ? dy : dz);
      atomicAdd(out + (size_t)A.ri * 3 + lg, d * sc);
    }

    A = B;
    pra0 = qra0; pra1 = qra1;
    pca0 = qca0; pca1 = qca1;
  }
}

extern "C" void kernel_launch(void* const* d_in, const int* in_sizes, int n_in,
                              void* d_out, int out_size, void* d_ws, size_t ws_size,
                              hipStream_t stream) {
  const float* h         = (const float*)d_in[0];
  const float* pos       = (const float*)d_in[1];
  const float* edge_attr = (const float*)d_in[2];
  const float* dist      = (const float*)d_in[3];
  const float* te        = (const float*)d_in[4];
  const float* tW        = (const float*)d_in[5];
  const float* tb        = (const float*)d_in[6];
  const float* iW        = (const float*)d_in[7];
  const float* ib        = (const float*)d_in[8];
  const float* c1W       = (const float*)d_in[9];
  const float* c1b       = (const float*)d_in[10];
  const float* c2W       = (const float*)d_in[11];
  const float* cn        = (const float*)d_in[12];
  const int*   eidx      = (const int*)d_in[13];
  float* out = (float*)d_out;

  char* ws = (char*)d_ws;
  u32*   P      = (u32*)(ws);                    // 40000*256 B (fp8) = 10,240,000 B
  u16*   wPt    = (u16*)(ws + 10240000);         // 65,536 B
  u16*   wadWt  = (u16*)(ws + 10305536);         // 16,384 B
  u16*   c1Wt   = (u16*)(ws + 10321920);         // 32,768 B
  float* film   = (float*)(ws + 10354688);       // 1,024 B
  float* biasp  = (float*)(ws + 10355712);       // 512 B

  hipLaunchKernelGGL(prep_film_kernel,    dim3(1),    dim3(256), 0, stream, te, tW, tb, film);
  hipLaunchKernelGGL(prep_weights_kernel, dim3(225),  dim3(256), 0, stream,
                     iW, c1W, film, c1b, wPt, wadWt, c1Wt, biasp);
  hipLaunchKernelGGL(prep_P_kernel,       dim3(625),  dim3(256), 0, stream,
                     h, wPt, ib, pos, P, out);
  hipLaunchKernelGGL(edge_kernel,         dim3(GRID), dim3(512), 0, stream,
                     pos, edge_attr, dist, c2W, cn, eidx,
                     P, wadWt, c1Wt, biasp, out);
}

// Round 22
// 96.139 us; speedup vs baseline: 3.7787x; 1.0347x over previous
//
#include <hip/hip_runtime.h>
#include <hip/hip_bf16.h>
#include <stdint.h>

#define NN 40000
#define EE 640000
#define HD 128
#define TDIM 128
#define TB 128
#define NTILES (EE / TB)   // 5000
#define GRID 768           // persistent: 3 blocks/CU target (33.8 KB LDS, ~82 regs)

typedef short  s16x8 __attribute__((ext_vector_type(8)));
typedef float  f32x2 __attribute__((ext_vector_type(2)));
typedef float  f32x4 __attribute__((ext_vector_type(4)));
typedef unsigned short u16;
typedef unsigned int   u32;

#define PSCL 8.0f        // P stored x8 in fp8 e4m3
#define PDSC 0.125f
#define WSCALE 16.0f     // GEMM2 weights stored x16 in fp8; descale 1/16 after MFMA
#define WDSC 0.0625f

__device__ __forceinline__ u32 cvtpk(float lo, float hi) {
  u32 r; asm("v_cvt_pk_bf16_f32 %0, %1, %2" : "=v"(r) : "v"(lo), "v"(hi)); return r;
}
__device__ __forceinline__ u16 f2b(float f) {
  union { float f; u32 u; } x; x.f = f;
  u32 r = x.u + 0x7fffu + ((x.u >> 16) & 1u);
  return (u16)(r >> 16);
}

// ---- launch 1: FiLM params: film[0:128]=shift, film[128:256]=1+scale ----
__global__ void prep_film_kernel(const float* __restrict__ te, const float* __restrict__ tW,
                                 const float* __restrict__ tb, float* __restrict__ film) {
  __shared__ float s[TDIM];
  int t = threadIdx.x;
  if (t < TDIM) { float v = te[t]; s[t] = v * __builtin_amdgcn_rcpf(1.f + __expf(-v)); }
  __syncthreads();
  float acc = tb[t];
  #pragma unroll 8
  for (int k = 0; k < TDIM; ++k) acc = fmaf(s[k], tW[k * 256 + t], acc);
  film[t] = (t >= 128) ? (1.f + acc) : acc;
}

// ---- launch 2 (fused): wPt | wadWt(bf16) | c1Wt(fp8) | biasp ----
//  blocks [0,128):   wPt[256][128] bf16
//  blocks [128,160): GEMM1 bf16 fragment-ordered (champion layout)
//  blocks [160,192): GEMM2 fp8 pairs, k-permuted (R19-validated layout)
//  block 192:        biasp
__global__ void prep_weights_kernel(const float* __restrict__ iW,
                                    const float* __restrict__ c1W,
                                    const float* __restrict__ film,
                                    const float* __restrict__ c1b,
                                    u16* __restrict__ wPt,
                                    u16* __restrict__ wadWt,
                                    u16* __restrict__ c1Wt,
                                    float* __restrict__ biasp) {
  int b = blockIdx.x, t = threadIdx.x;
  if (b < 128) {
    int idx = b * 256 + t;                 // < 32768
    int c = idx >> 7, k = idx & 127;
    wPt[idx] = f2b(iW[((c >> 7) * 128 + k) * HD + (c & 127)]);
  } else if (b < 160) {
    int idx = (b - 128) * 256 + t;         // < 8192 bf16
    int j = idx & 7, l15 = (idx >> 3) & 15, n = (idx >> 7) & 7, lg = (idx >> 10) & 3, ks = idx >> 12;
    int row = n * 16 + l15;
    int k = ks * 32 + lg * 8 + j;
    wadWt[idx] = f2b(iW[(256 + k) * HD + row]);
  } else if (b < 192) {
    int pidx = (b - 160) * 256 + t;        // < 8192 fp8 pairs
    int idx = pidx * 2;
    int j0 = idx & 7, l15 = (idx >> 3) & 15, n = (idx >> 7) & 7, lg = (idx >> 10) & 3, kq = idx >> 12;
    int row = n * 16 + l15;
    int ch0 = (kq * 2 + (j0 >> 2)) * 16 + lg * 4 + (j0 & 3);
    int ch1 = (kq * 2 + ((j0 + 1) >> 2)) * 16 + lg * 4 + ((j0 + 1) & 3);
    float v0 = WSCALE * film[128 + ch0] * c1W[ch0 * HD + row];
    float v1 = WSCALE * film[128 + ch1] * c1W[ch1 * HD + row];
    u32 p = __builtin_amdgcn_cvt_pk_fp8_f32(v0, v1, 0, false);
    c1Wt[pidx] = (u16)p;
  } else if (t < 128) {
    float acc = c1b[t];
    #pragma unroll 8
    for (int k = 0; k < 128; ++k) acc = fmaf(film[k], c1W[k * HD + t], acc);
    biasp[t] = acc;
  }
}

// ---- launch 3: P[node] = 64 u32 words of fp8 (x8), fragment-permuted; + pos copy ----
__global__ __launch_bounds__(256) void prep_P_kernel(const float* __restrict__ h,
                                                     const u16* __restrict__ wPt,
                                                     const float* __restrict__ ib,
                                                     const float* __restrict__ pos,
                                                     u32* __restrict__ P,
                                                     float* __restrict__ out) {
  __shared__ u16 sWp[256][136];
  __shared__ float sib[HD];
  int t = threadIdx.x;
  {
    int ci = blockIdx.x * 192 + t;
    if (t < 192) out[ci] = pos[ci];
  }
  if (t < 128) sib[t] = ib[t];
  {
    const u16* src = wPt + t * 128;
    #pragma unroll
    for (int i = 0; i < 16; ++i)
      *(uint4*)&sWp[t][i * 8] = *(const uint4*)(src + i * 8);
  }
  int wave = t >> 6, lane = t & 63, l15 = lane & 15, lg = lane >> 4;
  int node = blockIdx.x * 64 + wave * 16 + l15;
  uint4 hb[4];
  const float* hr = h + (size_t)node * HD + lg * 8;
  #pragma unroll
  for (int c = 0; c < 4; ++c) {
    float4 a = *(const float4*)(hr + c * 32);
    float4 b = *(const float4*)(hr + c * 32 + 4);
    hb[c].x = cvtpk(a.x, a.y); hb[c].y = cvtpk(a.z, a.w);
    hb[c].z = cvtpk(b.x, b.y); hb[c].w = cvtpk(b.z, b.w);
  }
  __syncthreads();
  f32x4 acc[16];
  #pragma unroll
  for (int n = 0; n < 16; ++n) acc[n] = (f32x4){0.f, 0.f, 0.f, 0.f};
  #pragma unroll
  for (int c = 0; c < 4; ++c) {
    s16x8 bF = *(const s16x8*)&hb[c];
    #pragma unroll
    for (int n = 0; n < 16; ++n) {
      s16x8 aF = *(const s16x8*)&sWp[n * 16 + l15][c * 32 + lg * 8];
      acc[n] = __builtin_amdgcn_mfma_f32_16x16x32_bf16(aF, bF, acc[n], 0, 0, 0);
    }
  }
  u32* dst = P + (size_t)node * 64;
  #pragma unroll
  for (int n = 0; n < 16; ++n) {
    int side = n >> 3;
    int cb = (n & 7) * 16 + lg * 4;
    float a0 = acc[n][0], a1 = acc[n][1], a2 = acc[n][2], a3 = acc[n][3];
    if (side == 0) { a0 += sib[cb]; a1 += sib[cb + 1]; a2 += sib[cb + 2]; a3 += sib[cb + 3]; }
    u32 w = __builtin_amdgcn_cvt_pk_fp8_f32(PSCL * a0, PSCL * a1, 0, false);
    w = __builtin_amdgcn_cvt_pk_fp8_f32(PSCL * a2, PSCL * a3, w, true);
    dst[side * 32 + lg * 8 + (n & 7)] = w;
  }
}

// ---- small prefetch state ----
struct PfS {
  int ri, ci;
  float4 a0, a1, d0, d1;
  float p0x, p0y, p0z, p1x, p1y, p1z;
};

// ---- launch 4: persistent fused edge kernel (fp8 P, bf16 GEMM1, fp8 GEMM2) ----
__global__ __launch_bounds__(512, 4) void edge_kernel(
    const float* __restrict__ pos,
    const float* __restrict__ edge_attr,
    const float* __restrict__ dist,
    const float* __restrict__ c2w,
    const float* __restrict__ cn_scale,
    const int*   __restrict__ eidx,
    const u32*   __restrict__ P,       // [N][64] u32 of fp8(x8), fragment-permuted
    const u16*   __restrict__ wadWt,   // 16 KB bf16 GEMM1 weights, fragment-ordered
    const u16*   __restrict__ c1Wt,    // 16 KB fp8 GEMM2 weights (x16, k-permuted)
    const float* __restrict__ biasp,   // [128]
    float*       __restrict__ out)
{
  __shared__ u16   sW1[8192];    // 16 KB bf16
  __shared__ u16   sW2[8192];    // 16 KB fp8
  __shared__ float sC1b[HD];
  __shared__ float sC2w[HD];

  const int t    = threadIdx.x;
  const int lane = t & 63;
  const int wave = t >> 6;        // 0..7
  const int l15  = lane & 15;
  const int lg   = lane >> 4;
  const int wv   = wave * 16 + l15;   // edge offset in tile, 0..127

  if (t < HD) { sC1b[t] = biasp[t]; sC2w[t] = c2w[t]; }
  {
    const uint4* s1 = (const uint4*)wadWt;   // 1024 uint4
    uint4* d1 = (uint4*)sW1;
    #pragma unroll
    for (int i = 0; i < 2; ++i) d1[t + i * 512] = s1[t + i * 512];
    const uint4* s2 = (const uint4*)c1Wt;    // 1024 uint4
    uint4* d2 = (uint4*)sW2;
    #pragma unroll
    for (int i = 0; i < 2; ++i) d2[t + i * 512] = s2[t + i * 512];
  }

  const float cns = cn_scale[0];
  const int bbase = lg * 2048 + l15 * 16;   // GEMM1 bf16: byte base in each 8KB k-panel
  const int bb8   = lg * 1024 + l15 * 8;    // GEMM2 fp8:  byte base in each 4KB k-panel

  auto pf_idx_ad = [&](PfS& p, int tile) {
    int e = tile * TB + wv;
    p.ri = eidx[e];
    p.ci = eidx[EE + e];
    const float* pa = edge_attr + (size_t)e * 32 + lg * 8;
    const float* pd = dist      + (size_t)e * 32 + lg * 8;
    p.a0 = *(const float4*)(pa); p.a1 = *(const float4*)(pa + 4);
    p.d0 = *(const float4*)(pd); p.d1 = *(const float4*)(pd + 4);
  };
  auto pf_pos = [&](PfS& p) {
    p.p0x = pos[p.ri * 3 + 0]; p.p0y = pos[p.ri * 3 + 1]; p.p0z = pos[p.ri * 3 + 2];
    p.p1x = pos[p.ci * 3 + 0]; p.p1y = pos[p.ci * 3 + 1]; p.p1z = pos[p.ci * 3 + 2];
  };

  PfS A, B;
  pf_idx_ad(A, blockIdx.x);
  pf_pos(A);

  // prologue: P gathers (fp8: 2 uint4 per side)
  uint4 pra0, pra1, pca0, pca1;
  {
    const u32* pr = P + (size_t)A.ri * 64 + lg * 8;
    const u32* pc = P + (size_t)A.ci * 64 + 32 + lg * 8;
    pra0 = *(const uint4*)(pr); pra1 = *(const uint4*)(pr + 4);
    pca0 = *(const uint4*)(pc); pca1 = *(const uint4*)(pc + 4);
  }

  __syncthreads();   // only barrier: weights + consts visible

  for (int tile = blockIdx.x; tile < NTILES; tile += GRID) {
    int tn = tile + GRID; if (tn >= NTILES) tn = tile;

    // (1) next tile's independent loads — in flight across this tile
    pf_idx_ad(B, tn);

    // (2) GEMM1 (bf16): Q = [attr|dist] @ iW_ad, immediate-offset LDS reads
    uint4 ef0, ef1;
    ef0.x = cvtpk(A.a0.x, A.a0.y); ef0.y = cvtpk(A.a0.z, A.a0.w);
    ef0.z = cvtpk(A.a1.x, A.a1.y); ef0.w = cvtpk(A.a1.z, A.a1.w);
    ef1.x = cvtpk(A.d0.x, A.d0.y); ef1.y = cvtpk(A.d0.z, A.d0.w);
    ef1.z = cvtpk(A.d1.x, A.d1.y); ef1.w = cvtpk(A.d1.z, A.d1.w);

    f32x4 acc[8];
    #pragma unroll
    for (int n = 0; n < 8; ++n) acc[n] = (f32x4){0.f, 0.f, 0.f, 0.f};
    #pragma unroll
    for (int ks = 0; ks < 2; ++ks) {
      s16x8 bF = (ks == 0) ? *(const s16x8*)&ef0 : *(const s16x8*)&ef1;
      #pragma unroll
      for (int n = 0; n < 8; ++n) {
        s16x8 aF = *(const s16x8*)((const char*)sW1 + ks * 8192 + bbase + n * 256);
        acc[n] = __builtin_amdgcn_mfma_f32_16x16x32_bf16(aF, bF, acc[n], 0, 0, 0);
      }
    }

    // (3) x = Q + (P_r + P_c)/8; LN stats with 4-way partial accumulators
    float x[8][4];
    float s0=0.f,s1=0.f,s2=0.f,s3=0.f, q0=0.f,q1=0.f,q2=0.f,q3=0.f;
    #pragma unroll
    for (int i = 0; i < 2; ++i) {
      uint4 wa = (i == 0) ? pra0 : pra1;
      uint4 wc = (i == 0) ? pca0 : pca1;
      #pragma unroll
      for (int k = 0; k < 4; ++k) {
        int n = i * 4 + k;
        u32 aw = (k == 0) ? wa.x : (k == 1) ? wa.y : (k == 2) ? wa.z : wa.w;
        u32 cw = (k == 0) ? wc.x : (k == 1) ? wc.y : (k == 2) ? wc.z : wc.w;
        f32x2 a01 = __builtin_amdgcn_cvt_pk_f32_fp8(aw, false);
        f32x2 a23 = __builtin_amdgcn_cvt_pk_f32_fp8(aw, true);
        f32x2 c01 = __builtin_amdgcn_cvt_pk_f32_fp8(cw, false);
        f32x2 c23 = __builtin_amdgcn_cvt_pk_f32_fp8(cw, true);
        float v0 = fmaf(a01[0] + c01[0], PDSC, acc[n][0]);
        float v1 = fmaf(a01[1] + c01[1], PDSC, acc[n][1]);
        float v2 = fmaf(a23[0] + c23[0], PDSC, acc[n][2]);
        float v3 = fmaf(a23[1] + c23[1], PDSC, acc[n][3]);
        x[n][0] = v0; x[n][1] = v1; x[n][2] = v2; x[n][3] = v3;
        s0 += v0; s1 += v1; s2 += v2; s3 += v3;
        q0 = fmaf(v0,v0,q0); q1 = fmaf(v1,v1,q1);
        q2 = fmaf(v2,v2,q2); q3 = fmaf(v3,v3,q3);
      }
    }
    float sum = (s0 + s1) + (s2 + s3);
    float sq  = (q0 + q1) + (q2 + q3);
    sum += __shfl_xor(sum, 16); sum += __shfl_xor(sum, 32);
    sq  += __shfl_xor(sq,  16); sq  += __shfl_xor(sq,  32);
    float mean = sum * (1.f / 128.f);
    float var  = sq  * (1.f / 128.f) - mean * mean;
    float LA = rsqrtf(var + 1e-6f);
    float LB = -mean * LA;

    // (4) x-hat -> fp8 words (GEMM2 B-operand, k-permuted)
    u32 xp[8];
    #pragma unroll
    for (int n = 0; n < 8; ++n) {
      float y0 = fmaf(x[n][0], LA, LB);
      float y1 = fmaf(x[n][1], LA, LB);
      float y2 = fmaf(x[n][2], LA, LB);
      float y3 = fmaf(x[n][3], LA, LB);
      u32 w = __builtin_amdgcn_cvt_pk_fp8_f32(y0, y1, 0, false);
      w = __builtin_amdgcn_cvt_pk_fp8_f32(y2, y3, w, true);
      xp[n] = w;
    }

    // (5) GEMM2 (fp8): reuse acc; B from registers, A via immediate-offset ds_read_b64
    #pragma unroll
    for (int n = 0; n < 8; ++n) acc[n] = (f32x4){0.f, 0.f, 0.f, 0.f};
    #pragma unroll
    for (int kq = 0; kq < 4; ++kq) {
      long xF = (long)(((unsigned long long)xp[2*kq+1] << 32) | xp[2*kq]);
      #pragma unroll
      for (int n = 0; n < 8; ++n) {
        long aF = *(const long*)((const char*)sW2 + kq * 4096 + bb8 + n * 128);
        acc[n] = __builtin_amdgcn_mfma_f32_16x16x32_fp8_fp8(aF, xF, acc[n], 0, 0, 0);
      }
    }

    // (6) silu -> dot(c2W) with 4-way partial chains (descale 1/16)
    float z0=0.f, z1=0.f, z2=0.f, z3=0.f;
    #pragma unroll
    for (int n = 0; n < 8; ++n) {
      int cb = n * 16 + lg * 4;
      f32x4 cb4 = *(const f32x4*)&sC1b[cb];
      f32x4 cw4 = *(const f32x4*)&sC2w[cb];
      float y0 = fmaf(acc[n][0], WDSC, cb4[0]);
      float y1 = fmaf(acc[n][1], WDSC, cb4[1]);
      float y2 = fmaf(acc[n][2], WDSC, cb4[2]);
      float y3 = fmaf(acc[n][3], WDSC, cb4[3]);
      z0 = fmaf(y0 * __builtin_amdgcn_rcpf(1.f + __expf(-y0)), cw4[0], z0);
      z1 = fmaf(y1 * __builtin_amdgcn_rcpf(1.f + __expf(-y1)), cw4[1], z1);
      z2 = fmaf(y2 * __builtin_amdgcn_rcpf(1.f + __expf(-y2)), cw4[2], z2);
      z3 = fmaf(y3 * __builtin_amdgcn_rcpf(1.f + __expf(-y3)), cw4[3], z3);
    }
    float z = (z0 + z1) + (z2 + z3);
    z += __shfl_xor(z, 16); z += __shfl_xor(z, 32);

    // (7) depth-1 prefetch: next tile's pos + P words
    pf_pos(B);
    uint4 qra0, qra1, qca0, qca1;
    {
      const u32* pr = P + (size_t)B.ri * 64 + lg * 8;
      const u32* pc = P + (size_t)B.ci * 64 + 32 + lg * 8;
      qra0 = *(const uint4*)(pr); qra1 = *(const uint4*)(pr + 4);
      qca0 = *(const uint4*)(pc); qca1 = *(const uint4*)(pc + 4);
    }

    // (8) tanh -> scatter
    if (lg < 3) {
      float zc = fminf(fmaxf(z, -15.f), 15.f);
      float ez = __expf(2.f * zc);
      float inv = (ez - 1.f) * __builtin_amdgcn_rcpf(ez + 1.f);
      float dx = A.p0x - A.p1x, dy = A.p0y - A.p1y, dz = A.p0z - A.p1z;
      float nrm = sqrtf(fmaf(dx, dx, fmaf(dy, dy, dz * dz)));
      float sc  = cns * inv * __builtin_amdgcn_rcpf(fmaxf(nrm, 1e-8f));
      float d   = (lg == 0) ? dx : ((lg == 1) ? dy : dz);
      atomicAdd(out + (size_t)A.ri * 3 + lg, d * sc);
    }

    A = B;
    pra0 = qra0; pra1 = qra1;
    pca0 = qca0; pca1 = qca1;
  }
}

extern "C" void kernel_launch(void* const* d_in, const int* in_sizes, int n_in,
                              void* d_out, int out_size, void* d_ws, size_t ws_size,
                              hipStream_t stream) {
  const float* h         = (const float*)d_in[0];
  const float* pos       = (const float*)d_in[1];
  const float* edge_attr = (const float*)d_in[2];
  const float* dist      = (const float*)d_in[3];
  const float* te        = (const float*)d_in[4];
  const float* tW        = (const float*)d_in[5];
  const float* tb        = (const float*)d_in[6];
  const float* iW        = (const float*)d_in[7];
  const float* ib        = (const float*)d_in[8];
  const float* c1W       = (const float*)d_in[9];
  const float* c1b       = (const float*)d_in[10];
  const float* c2W       = (const float*)d_in[11];
  const float* cn        = (const float*)d_in[12];
  const int*   eidx      = (const int*)d_in[13];
  float* out = (float*)d_out;

  char* ws = (char*)d_ws;
  u32*   P      = (u32*)(ws);                    // 40000*256 B (fp8) = 10,240,000 B
  u16*   wPt    = (u16*)(ws + 10240000);         // 65,536 B
  u16*   wadWt  = (u16*)(ws + 10305536);         // 16,384 B (bf16)
  u16*   c1Wt   = (u16*)(ws + 10321920);         // 16,384 B (fp8)
  float* film   = (float*)(ws + 10338304);       // 1,024 B
  float* biasp  = (float*)(ws + 10339328);       // 512 B

  hipLaunchKernelGGL(prep_film_kernel,    dim3(1),    dim3(256), 0, stream, te, tW, tb, film);
  hipLaunchKernelGGL(prep_weights_kernel, dim3(193),  dim3(256), 0, stream,
                     iW, c1W, film, c1b, wPt, wadWt, c1Wt, biasp);
  hipLaunchKernelGGL(prep_P_kernel,       dim3(625),  dim3(256), 0, stream,
                     h, wPt, ib, pos, P, out);
  hipLaunchKernelGGL(edge_kernel,         dim3(GRID), dim3(512), 0, stream,
                     pos, edge_attr, dist, c2W, cn, eidx,
                     P, wadWt, c1Wt, biasp, out);
}